// Round 4
// baseline (271.311 us; speedup 1.0000x reference)
//
#include <hip/hip_runtime.h>

// out[b,y,x] = sum_c sum_{p,q in [0,4)} feat1[b,c,y+p-2,x+q-2] * feat2[b,c,p,q]
// B=4096, C=512, H=W=4.
//
// Round-2 rocprof: 100us, 1.33 TB/s (16%), VALUBusy 11%, VGPR 24 -> latency-bound:
// compiler minimized registers (serialized loads) and per-block burst/compute/
// barrier phases drained the memory queue. This version: one WAVE per b,
// 8 channels/lane over 8 chunks, register double-buffer prefetch, no LDS,
// no __syncthreads -> loads stream continuously (consume waits are vmcnt(8),
// never a full drain).

__global__ __launch_bounds__(256, 4) void corr_kernel(
        const float4* __restrict__ feat1,
        const float4* __restrict__ feat2,
        float* __restrict__ out, int B) {
    const int lane  = threadIdx.x & 63;
    const int wid   = blockIdx.x * 4 + (threadIdx.x >> 6);
    const int nwave = gridDim.x * 4;

    for (int b = wid; b < B; b += nwave) {
        const size_t bbase = (size_t)b * 512;   // channel base for this b

        float4 A[2][4], W[2][4];                // double-buffered chunk regs
        {   // prologue: chunk 0 (lane's channel = lane)
            const size_t idx = (bbase + lane) * 4;   // float4 units
            #pragma unroll
            for (int i = 0; i < 4; ++i) { A[0][i] = feat1[idx + i]; W[0][i] = feat2[idx + i]; }
        }

        float acc[16];
        #pragma unroll
        for (int i = 0; i < 16; ++i) acc[i] = 0.f;

        #pragma unroll
        for (int k = 0; k < 8; ++k) {           // 8 chunks x 64 lanes = 512 channels
            const int cur = k & 1, nxt = cur ^ 1;
            if (k < 7) {                        // issue next chunk's 8 loads first
                const size_t idx = (bbase + (size_t)(k + 1) * 64 + lane) * 4;
                #pragma unroll
                for (int i = 0; i < 4; ++i) { A[nxt][i] = feat1[idx + i]; W[nxt][i] = feat2[idx + i]; }
            }
            // Pin the prefetch above the compute so the scheduler can't sink it
            // to minimize registers (the round-2 failure mode, VGPR=24).
            __builtin_amdgcn_sched_barrier(0);

            const float a[16] = { A[cur][0].x, A[cur][0].y, A[cur][0].z, A[cur][0].w,
                                  A[cur][1].x, A[cur][1].y, A[cur][1].z, A[cur][1].w,
                                  A[cur][2].x, A[cur][2].y, A[cur][2].z, A[cur][2].w,
                                  A[cur][3].x, A[cur][3].y, A[cur][3].z, A[cur][3].w };
            const float w[16] = { W[cur][0].x, W[cur][0].y, W[cur][0].z, W[cur][0].w,
                                  W[cur][1].x, W[cur][1].y, W[cur][1].z, W[cur][1].w,
                                  W[cur][2].x, W[cur][2].y, W[cur][2].z, W[cur][2].w,
                                  W[cur][3].x, W[cur][3].y, W[cur][3].z, W[cur][3].w };

            // 144 compile-time-unrolled FMAs (OOB terms folded away)
            #pragma unroll
            for (int y = 0; y < 4; ++y)
            #pragma unroll
            for (int p = 0; p < 4; ++p) {
                const int u = y + p - 2;
                if (u < 0 || u > 3) continue;
                #pragma unroll
                for (int x = 0; x < 4; ++x)
                #pragma unroll
                for (int q = 0; q < 4; ++q) {
                    const int v = x + q - 2;
                    if (v < 0 || v > 3) continue;
                    acc[y*4 + x] = fmaf(a[u*4 + v], w[p*4 + q], acc[y*4 + x]);
                }
            }
        }

        // Value-splitting butterfly: step k pairs lanes differing in bit k; each
        // lane keeps the half of its components whose index-bit-k matches its
        // own lane-bit-k and receives the partner's matching half. After 4 steps
        // lane l holds component (l&15) summed over its 16-lane group; two plain
        // xor steps finish the wave. (Verified passing in round 2.)
        float v[16];
        #pragma unroll
        for (int i = 0; i < 16; ++i) v[i] = acc[i];
        #pragma unroll
        for (int k = 0; k < 4; ++k) {
            const int m = 1 << k;
            const int pairs = 8 >> k;
            const bool sel = (lane >> k) & 1;
            float wtmp[8];
            #pragma unroll
            for (int p = 0; p < pairs; ++p) {
                float keep = sel ? v[2*p+1] : v[2*p];
                float send = sel ? v[2*p]   : v[2*p+1];
                float recv = __shfl_xor(send, m, 64);
                wtmp[p] = keep + recv;
            }
            #pragma unroll
            for (int p = 0; p < pairs; ++p) v[p] = wtmp[p];
        }
        float r = v[0];
        r += __shfl_xor(r, 16, 64);
        r += __shfl_xor(r, 32, 64);

        if (lane < 16) out[(size_t)b * 16 + lane] = r;   // 64B contiguous store
    }
}

extern "C" void kernel_launch(void* const* d_in, const int* in_sizes, int n_in,
                              void* d_out, int out_size, void* d_ws, size_t ws_size,
                              hipStream_t stream) {
    const float4* feat1 = (const float4*)d_in[0];
    const float4* feat2 = (const float4*)d_in[1];
    float* out = (float*)d_out;
    const int B = in_sizes[0] / (512 * 16);   // 4096
    const int blocks = (B + 3) / 4;           // one wave per b, 4 waves/block
    corr_kernel<<<dim3(blocks), dim3(256), 0, stream>>>(feat1, feat2, out, B);
}